// Round 5
// baseline (999.495 us; speedup 1.0000x reference)
//
#include <hip/hip_runtime.h>

// GraphSAGE 3-layer: N=100000, E=3.2M, 128 -> 128 -> 128 -> 64.
// Round 5: sliced gather. xh/hh stored slice-major (8 slices x 16 cols);
// one slice = N*32B = 3.2MB < 4MiB per-XCD L2 -> gather feature reads become
// L2 hits. Gather runs 8 grid-phases (slice = blockIdx/bps, dispatch-order
// clustered). meanh stays row-major. mfma root-A stage + fp16 epilogue use
// sliced addressing (index math only; MFMA fragment layout unchanged).
// CSR build (2-level counting sort) unchanged from round 4.

#define NN 100000
#define CHUNK 8192

typedef _Float16 half_t;
typedef __attribute__((ext_vector_type(4))) _Float16 half4v;
typedef __attribute__((ext_vector_type(8))) _Float16 half8v;
typedef __attribute__((ext_vector_type(4))) float float4v;

// ---- Pass A: coarse histogram (LDS-privatized) ----
__global__ __launch_bounds__(256) void coarse_hist_kernel(const int* __restrict__ dst,
                                                          int* __restrict__ ghist, int E) {
    __shared__ int h[1024];
    int tid = threadIdx.x;
    for (int i = tid; i < 1024; i += 256) h[i] = 0;
    __syncthreads();
    int base = blockIdx.x * CHUNK;
    int nE = min(CHUNK, E - base);
    for (int i = tid; i < nE; i += 256) atomicAdd(&h[dst[base + i] >> 7], 1);
    __syncthreads();
    for (int i = tid; i < 1024; i += 256) {
        int v = h[i];
        if (v) atomicAdd(&ghist[i], v);
    }
}

// ---- Pass B: scan 1024 coarse bins ----
__global__ __launch_bounds__(1024) void coarse_scan_kernel(const int* __restrict__ ghist,
                                                           int* __restrict__ cptr,
                                                           int* __restrict__ cfill,
                                                           int* __restrict__ row_ptr,
                                                           int n, int E) {
    __shared__ int s[1024];
    int tid = threadIdx.x;
    s[tid] = ghist[tid];
    __syncthreads();
    for (int off = 1; off < 1024; off <<= 1) {
        int v = (tid >= off) ? s[tid - off] : 0;
        __syncthreads();
        s[tid] += v;
        __syncthreads();
    }
    int excl = (tid == 0) ? 0 : s[tid - 1];
    cptr[tid] = excl;
    cfill[tid] = excl;
    if (tid == 1023) {
        cptr[1024] = s[1023];
        row_ptr[n] = E;
    }
}

// ---- Pass C: partition edges into coarse buckets (packed u32) ----
__global__ __launch_bounds__(256) void partition_kernel(const int* __restrict__ src,
                                                        const int* __restrict__ dst,
                                                        int* __restrict__ cfill,
                                                        unsigned int* __restrict__ coarse,
                                                        int E) {
    __shared__ int h[1024];
    __shared__ int off[1024];
    __shared__ int gbase[1024];
    __shared__ int ssum[256];
    __shared__ unsigned int stage[CHUNK];
    int tid = threadIdx.x;
    for (int i = tid; i < 1024; i += 256) h[i] = 0;
    __syncthreads();
    int base = blockIdx.x * CHUNK;
    int nE = min(CHUNK, E - base);
    for (int i = tid; i < nE; i += 256) atomicAdd(&h[dst[base + i] >> 7], 1);
    __syncthreads();
    int b0 = tid * 4;
    int sum = h[b0] + h[b0 + 1] + h[b0 + 2] + h[b0 + 3];
    ssum[tid] = sum;
    __syncthreads();
    for (int o = 1; o < 256; o <<= 1) {
        int v = (tid >= o) ? ssum[tid - o] : 0;
        __syncthreads();
        ssum[tid] += v;
        __syncthreads();
    }
    int run = (tid == 0) ? 0 : ssum[tid - 1];
#pragma unroll
    for (int j = 0; j < 4; j++) { off[b0 + j] = run; run += h[b0 + j]; }
    __syncthreads();
    for (int i = tid; i < nE; i += 256) {
        int d = dst[base + i];
        int s_ = src[base + i];
        int bin = d >> 7;
        int pos = atomicAdd(&off[bin], 1);
        stage[pos] = ((unsigned)(d & 127) << 17) | (unsigned)s_;
    }
    __syncthreads();
#pragma unroll
    for (int j = 0; j < 4; j++) {
        int b = b0 + j;
        if (h[b]) gbase[b] = atomicAdd(&cfill[b], h[b]);
    }
#pragma unroll
    for (int j = 0; j < 4; j++) {
        int b = b0 + j;
        int c = h[b];
        int lstart = off[b] - c;
        int gs = gbase[b];
        for (int k = 0; k < c; k++) coarse[gs + k] = stage[lstart + k];
    }
}

// ---- Pass D: fine sort within each coarse bucket ----
__global__ __launch_bounds__(256) void fine_sort_kernel(const unsigned int* __restrict__ coarse,
                                                        const int* __restrict__ cptr,
                                                        int* __restrict__ row_ptr,
                                                        int* __restrict__ sorted_src, int n) {
    __shared__ int fh[128];
    __shared__ int foff[128];
    int b = blockIdx.x;
    int beg = cptr[b], end = cptr[b + 1];
    int nb = end - beg;
    int tid = threadIdx.x;
    if (tid < 128) fh[tid] = 0;
    __syncthreads();
    for (int i = tid; i < nb; i += 256) atomicAdd(&fh[coarse[beg + i] >> 17], 1);
    __syncthreads();
    if (tid < 128) foff[tid] = fh[tid];
    __syncthreads();
    for (int o = 1; o < 128; o <<= 1) {
        int v = 0;
        if (tid < 128 && tid >= o) v = foff[tid - o];
        __syncthreads();
        if (tid < 128) foff[tid] += v;
        __syncthreads();
    }
    if (tid < 128) {
        int node = b * 128 + tid;
        if (node < n) row_ptr[node] = beg + foff[tid] - fh[tid];
        foff[tid] -= fh[tid];
    }
    __syncthreads();
    for (int i = tid; i < nb; i += 256) {
        unsigned int p = coarse[beg + i];
        int f = p >> 17;
        int pos = atomicAdd(&foff[f], 1);
        sorted_src[beg + pos] = (int)(p & 0x1FFFF);
    }
}

// ---- fp32 (row-major) -> fp16 sliced: out[(slice*N+node)*16 + col] ----
__global__ __launch_bounds__(256) void cast_f2h_sliced(const float* __restrict__ in,
                                                       half_t* __restrict__ out) {
    int idx = blockIdx.x * 256 + threadIdx.x;  // N*16 threads, 8 floats each
    if (idx >= NN * 16) return;
    int half8 = idx & 1;
    int rem = idx >> 1;
    int node = rem % NN;
    int slice = rem / NN;
    const float* p = in + (size_t)node * 128 + slice * 16 + half8 * 8;
    float4 v0 = *(const float4*)p;
    float4 v1 = *(const float4*)(p + 4);
    half8v r = {(half_t)v0.x, (half_t)v0.y, (half_t)v0.z, (half_t)v0.w,
                (half_t)v1.x, (half_t)v1.y, (half_t)v1.z, (half_t)v1.w};
    *(half8v*)(out + ((size_t)slice * NN + node) * 16 + half8 * 8) = r;
}

// ---- weight prep: fragment-contiguous fp16 ----
template <int C_IN, int C_OUT>
__global__ void prep_w(const float* __restrict__ W, half_t* __restrict__ B) {
    constexpr int NCT = C_OUT / 16;
    int t = blockIdx.x * blockDim.x + threadIdx.x;
    if (t >= C_IN * C_OUT) return;
    int jj = t & 7;
    int kq = (t >> 3) & 3;
    int c = (t >> 5) & 15;
    int ct = (t >> 9) % NCT;
    int chunk = t / (512 * NCT);
    int k = chunk * 32 + kq * 8 + jj;
    int j = ct * 16 + c;
    B[t] = (half_t)W[(size_t)j * C_IN + k];
}

// ---- sliced gather mean ----
// grid = 8 slices x (N/8 node-blocks), slice-major so phases cluster in time.
// 32-lane group per node; 4 lanes per edge (half4v = 8B of the 32B slice row);
// 8 edges in flight per group; xor-shuffle reduce; write 16 cols of meanh.
__global__ __launch_bounds__(256) void gather_mean_sliced(
    const half_t* __restrict__ hs, const int* __restrict__ row_ptr,
    const int* __restrict__ sorted_src, half_t* __restrict__ mean, int n) {
    const int bps = NN / 8;  // node-blocks per slice (N divisible by 8)
    int slice = blockIdx.x / bps;
    int nb = blockIdx.x % bps;
    int tid = threadIdx.x;
    int node = nb * 8 + (tid >> 5);
    if (node >= n) return;
    int lane = tid & 31;
    int sub = lane >> 2;   // edge subgroup 0..7
    int cq = lane & 3;     // column quad 0..3
    int beg = row_ptr[node], end = row_ptr[node + 1];
    const half_t* base = hs + (size_t)slice * (NN * 16) + cq * 4;
    float a0 = 0.f, a1 = 0.f, a2 = 0.f, a3 = 0.f;
    for (int j0 = beg; j0 < end; j0 += 8) {
        int j = j0 + sub;
        if (j < end) {
            int s = sorted_src[j];
            half4v v = *(const half4v*)(base + (size_t)s * 16);
            a0 += (float)v.x; a1 += (float)v.y; a2 += (float)v.z; a3 += (float)v.w;
        }
    }
#pragma unroll
    for (int m = 4; m <= 16; m <<= 1) {
        a0 += __shfl_xor(a0, m);
        a1 += __shfl_xor(a1, m);
        a2 += __shfl_xor(a2, m);
        a3 += __shfl_xor(a3, m);
    }
    if ((lane & 28) == 0) {
        float inv = (end > beg) ? 1.0f / (float)(end - beg) : 0.0f;
        half4v r = {(half_t)(a0 * inv), (half_t)(a1 * inv), (half_t)(a2 * inv), (half_t)(a3 * inv)};
        *(half4v*)(mean + (size_t)node * 128 + slice * 16 + cq * 4) = r;
    }
}

// ---- MFMA layer: out = relu?( mean@Wl^T + bias + root@Wr^T ) ----
// mean: row-major. root: SLICED. out16: SLICED (C_OUT=128). out32: row-major.
template <int C_OUT, bool RELU, bool OUT32>
__global__ __launch_bounds__(256) void mfma_layer(
    const half_t* __restrict__ rootA, const half_t* __restrict__ meanA,
    const half_t* __restrict__ Bl, const half_t* __restrict__ Br,
    const float* __restrict__ bias, float* __restrict__ out32,
    half_t* __restrict__ out16, int n) {
    constexpr int NCT = C_OUT / 16;
    int tid = threadIdx.x;
    int w = tid >> 6;
    int l = tid & 63;
    int c = l & 15;
    int q = l >> 4;
    int row = blockIdx.x * 64 + w * 16 + c;
    int rowc = min(row, n - 1);

    float4v acc[NCT];
#pragma unroll
    for (int i = 0; i < NCT; i++) acc[i] = (float4v){0.f, 0.f, 0.f, 0.f};

    // mean stage (row-major A)
    {
        const half_t* A = meanA + (size_t)rowc * 128 + q * 8;
        const half_t* B = Bl + (size_t)(c * 4 + q) * 8;
#pragma unroll
        for (int ch = 0; ch < 4; ch++) {
            half8v a = *(const half8v*)(A + ch * 32);
            half8v b[NCT];
#pragma unroll
            for (int t2 = 0; t2 < NCT; t2++)
                b[t2] = *(const half8v*)(B + (size_t)ch * (NCT * 512) + t2 * 512);
#pragma unroll
            for (int t2 = 0; t2 < NCT; t2++)
                acc[t2] = __builtin_amdgcn_mfma_f32_16x16x32_f16(a, b[t2], acc[t2], 0, 0, 0);
        }
    }
    // root stage (sliced A): k = ch*32 + q*8 -> slice = 2ch + (q>>1), off = (q&1)*8
    {
        const half_t* B = Br + (size_t)(c * 4 + q) * 8;
        const half_t* A = rootA + (size_t)rowc * 16 + (q & 1) * 8;
#pragma unroll
        for (int ch = 0; ch < 4; ch++) {
            int slice = 2 * ch + (q >> 1);
            half8v a = *(const half8v*)(A + (size_t)slice * (NN * 16));
            half8v b[NCT];
#pragma unroll
            for (int t2 = 0; t2 < NCT; t2++)
                b[t2] = *(const half8v*)(B + (size_t)ch * (NCT * 512) + t2 * 512);
#pragma unroll
            for (int t2 = 0; t2 < NCT; t2++)
                acc[t2] = __builtin_amdgcn_mfma_f32_16x16x32_f16(a, b[t2], acc[t2], 0, 0, 0);
        }
    }

    int orow0 = blockIdx.x * 64 + w * 16 + q * 4;
#pragma unroll
    for (int t2 = 0; t2 < NCT; t2++) {
        int col = t2 * 16 + c;
        float bv = bias[col];
#pragma unroll
        for (int r = 0; r < 4; r++) {
            int nrow = orow0 + r;
            if (nrow < n) {
                float v = acc[t2][r] + bv;
                if (RELU) v = fmaxf(v, 0.f);
                if (OUT32) out32[(size_t)nrow * C_OUT + col] = v;
                else       out16[((size_t)t2 * NN + nrow) * 16 + c] = (half_t)v;
            }
        }
    }
}

extern "C" void kernel_launch(void* const* d_in, const int* in_sizes, int n_in,
                              void* d_out, int out_size, void* d_ws, size_t ws_size,
                              hipStream_t stream) {
    const float* x   = (const float*)d_in[0];
    const int*   ei  = (const int*)d_in[1];
    const float* Wl1 = (const float*)d_in[2];
    const float* bl1 = (const float*)d_in[3];
    const float* Wr1 = (const float*)d_in[4];
    const float* Wl2 = (const float*)d_in[5];
    const float* bl2 = (const float*)d_in[6];
    const float* Wr2 = (const float*)d_in[7];
    const float* Wl3 = (const float*)d_in[8];
    const float* bl3 = (const float*)d_in[9];
    const float* Wr3 = (const float*)d_in[10];

    const int N = NN;
    const int E = in_sizes[1] / 2;
    const int* src = ei;
    const int* dst = ei + E;

    char* ws = (char*)d_ws;
    half_t* xh    = (half_t*)ws;                      // N*128 sliced
    half_t* hh    = xh + (size_t)N * 128;             // N*128 sliced
    half_t* meanh = hh + (size_t)N * 128;             // N*128 row-major
    int* ghist    = (int*)(meanh + (size_t)N * 128);  // 1024
    int* cptr     = ghist + 1024;                     // 1025 (pad 1028)
    int* cfill    = cptr + 1028;                      // 1024
    int* row_ptr  = cfill + 1024;                     // N+1 (pad N+4)
    unsigned int* coarse = (unsigned int*)(row_ptr + N + 4);  // E
    int* sorted_src = (int*)(coarse + E);             // E
    half_t* Bl1 = (half_t*)(sorted_src + E);
    half_t* Br1 = Bl1 + 128 * 128;
    half_t* Bl2 = Br1 + 128 * 128;
    half_t* Br2 = Bl2 + 128 * 128;
    half_t* Bl3 = Br2 + 128 * 128;                    // 64*128
    half_t* Br3 = Bl3 + 64 * 128;

    // casts + weight prep (tiny)
    cast_f2h_sliced<<<(N * 16 + 255) / 256, 256, 0, stream>>>(x, xh);
    prep_w<128, 128><<<64, 256, 0, stream>>>(Wl1, Bl1);
    prep_w<128, 128><<<64, 256, 0, stream>>>(Wr1, Br1);
    prep_w<128, 128><<<64, 256, 0, stream>>>(Wl2, Bl2);
    prep_w<128, 128><<<64, 256, 0, stream>>>(Wr2, Br2);
    prep_w<128, 64><<<32, 256, 0, stream>>>(Wl3, Bl3);
    prep_w<128, 64><<<32, 256, 0, stream>>>(Wr3, Br3);

    // CSR build: two-level counting sort
    const int sort_blocks = (E + CHUNK - 1) / CHUNK;
    hipMemsetAsync(ghist, 0, 1024 * 4, stream);
    coarse_hist_kernel<<<sort_blocks, 256, 0, stream>>>(dst, ghist, E);
    coarse_scan_kernel<<<1, 1024, 0, stream>>>(ghist, cptr, cfill, row_ptr, N, E);
    partition_kernel<<<sort_blocks, 256, 0, stream>>>(src, dst, cfill, coarse, E);
    fine_sort_kernel<<<(N + 127) / 128, 256, 0, stream>>>(coarse, cptr, row_ptr, sorted_src, N);

    const int agg_blocks = (N / 8) * 8;  // (N/8 node-blocks) x 8 slices
    const int gemm_blocks = (N + 63) / 64;

    // Layer 1: xh -> hh (relu)
    gather_mean_sliced<<<agg_blocks, 256, 0, stream>>>(xh, row_ptr, sorted_src, meanh, N);
    mfma_layer<128, true, false><<<gemm_blocks, 256, 0, stream>>>(
        xh, meanh, Bl1, Br1, bl1, nullptr, hh, N);

    // Layer 2: hh -> hh (relu)
    gather_mean_sliced<<<agg_blocks, 256, 0, stream>>>(hh, row_ptr, sorted_src, meanh, N);
    mfma_layer<128, true, false><<<gemm_blocks, 256, 0, stream>>>(
        hh, meanh, Bl2, Br2, bl2, nullptr, hh, N);

    // Layer 3: hh -> d_out fp32 (no relu)
    gather_mean_sliced<<<agg_blocks, 256, 0, stream>>>(hh, row_ptr, sorted_src, meanh, N);
    mfma_layer<64, false, true><<<gemm_blocks, 256, 0, stream>>>(
        hh, meanh, Bl3, Br3, bl3, (float*)d_out, nullptr, N);
}

// Round 6
// 609.394 us; speedup vs baseline: 1.6401x; 1.6401x over previous
//
#include <hip/hip_runtime.h>

// GraphSAGE 3-layer: N=100000, E=3.2M, 128 -> 128 -> 128 -> 64.
// Round 6: revert round-5 slicing (index re-reads thrashed L2; ILP collapsed).
// Row-major fp16 features. Changes vs round 4:
//  - gather_mean: 16 lanes x 16B (dwordx4) per edge, unroll x4 -> 64B/lane
//    in flight (round 4 was 32B at 8B granularity). Latency-bound fix.
//  - layer 3 transform-before-aggregate: z = hh@Wl3^T (fp16), gather 128B
//    z-rows (half traffic, 12.8MB working set), out = meanz + bl3 + hh@Wr3^T.
//  - 6 prep_w launches merged into 1.
// CSR build (2-level counting sort) unchanged.

#define NN 100000
#define CHUNK 8192

typedef _Float16 half_t;
typedef __attribute__((ext_vector_type(4))) _Float16 half4v;
typedef __attribute__((ext_vector_type(8))) _Float16 half8v;
typedef __attribute__((ext_vector_type(4))) float float4v;

// ---- Pass A: coarse histogram (LDS-privatized) ----
__global__ __launch_bounds__(256) void coarse_hist_kernel(const int* __restrict__ dst,
                                                          int* __restrict__ ghist, int E) {
    __shared__ int h[1024];
    int tid = threadIdx.x;
    for (int i = tid; i < 1024; i += 256) h[i] = 0;
    __syncthreads();
    int base = blockIdx.x * CHUNK;
    int nE = min(CHUNK, E - base);
    for (int i = tid; i < nE; i += 256) atomicAdd(&h[dst[base + i] >> 7], 1);
    __syncthreads();
    for (int i = tid; i < 1024; i += 256) {
        int v = h[i];
        if (v) atomicAdd(&ghist[i], v);
    }
}

// ---- Pass B: scan 1024 coarse bins ----
__global__ __launch_bounds__(1024) void coarse_scan_kernel(const int* __restrict__ ghist,
                                                           int* __restrict__ cptr,
                                                           int* __restrict__ cfill,
                                                           int* __restrict__ row_ptr,
                                                           int n, int E) {
    __shared__ int s[1024];
    int tid = threadIdx.x;
    s[tid] = ghist[tid];
    __syncthreads();
    for (int off = 1; off < 1024; off <<= 1) {
        int v = (tid >= off) ? s[tid - off] : 0;
        __syncthreads();
        s[tid] += v;
        __syncthreads();
    }
    int excl = (tid == 0) ? 0 : s[tid - 1];
    cptr[tid] = excl;
    cfill[tid] = excl;
    if (tid == 1023) {
        cptr[1024] = s[1023];
        row_ptr[n] = E;
    }
}

// ---- Pass C: partition edges into coarse buckets (packed u32) ----
__global__ __launch_bounds__(256) void partition_kernel(const int* __restrict__ src,
                                                        const int* __restrict__ dst,
                                                        int* __restrict__ cfill,
                                                        unsigned int* __restrict__ coarse,
                                                        int E) {
    __shared__ int h[1024];
    __shared__ int off[1024];
    __shared__ int gbase[1024];
    __shared__ int ssum[256];
    __shared__ unsigned int stage[CHUNK];
    int tid = threadIdx.x;
    for (int i = tid; i < 1024; i += 256) h[i] = 0;
    __syncthreads();
    int base = blockIdx.x * CHUNK;
    int nE = min(CHUNK, E - base);
    for (int i = tid; i < nE; i += 256) atomicAdd(&h[dst[base + i] >> 7], 1);
    __syncthreads();
    int b0 = tid * 4;
    int sum = h[b0] + h[b0 + 1] + h[b0 + 2] + h[b0 + 3];
    ssum[tid] = sum;
    __syncthreads();
    for (int o = 1; o < 256; o <<= 1) {
        int v = (tid >= o) ? ssum[tid - o] : 0;
        __syncthreads();
        ssum[tid] += v;
        __syncthreads();
    }
    int run = (tid == 0) ? 0 : ssum[tid - 1];
#pragma unroll
    for (int j = 0; j < 4; j++) { off[b0 + j] = run; run += h[b0 + j]; }
    __syncthreads();
    for (int i = tid; i < nE; i += 256) {
        int d = dst[base + i];
        int s_ = src[base + i];
        int bin = d >> 7;
        int pos = atomicAdd(&off[bin], 1);
        stage[pos] = ((unsigned)(d & 127) << 17) | (unsigned)s_;
    }
    __syncthreads();
#pragma unroll
    for (int j = 0; j < 4; j++) {
        int b = b0 + j;
        if (h[b]) gbase[b] = atomicAdd(&cfill[b], h[b]);
    }
#pragma unroll
    for (int j = 0; j < 4; j++) {
        int b = b0 + j;
        int c = h[b];
        int lstart = off[b] - c;
        int gs = gbase[b];
        for (int k = 0; k < c; k++) coarse[gs + k] = stage[lstart + k];
    }
}

// ---- Pass D: fine sort within each coarse bucket ----
__global__ __launch_bounds__(256) void fine_sort_kernel(const unsigned int* __restrict__ coarse,
                                                        const int* __restrict__ cptr,
                                                        int* __restrict__ row_ptr,
                                                        int* __restrict__ sorted_src, int n) {
    __shared__ int fh[128];
    __shared__ int foff[128];
    int b = blockIdx.x;
    int beg = cptr[b], end = cptr[b + 1];
    int nb = end - beg;
    int tid = threadIdx.x;
    if (tid < 128) fh[tid] = 0;
    __syncthreads();
    for (int i = tid; i < nb; i += 256) atomicAdd(&fh[coarse[beg + i] >> 17], 1);
    __syncthreads();
    if (tid < 128) foff[tid] = fh[tid];
    __syncthreads();
    for (int o = 1; o < 128; o <<= 1) {
        int v = 0;
        if (tid < 128 && tid >= o) v = foff[tid - o];
        __syncthreads();
        if (tid < 128) foff[tid] += v;
        __syncthreads();
    }
    if (tid < 128) {
        int node = b * 128 + tid;
        if (node < n) row_ptr[node] = beg + foff[tid] - fh[tid];
        foff[tid] -= fh[tid];
    }
    __syncthreads();
    for (int i = tid; i < nb; i += 256) {
        unsigned int p = coarse[beg + i];
        int f = p >> 17;
        int pos = atomicAdd(&foff[f], 1);
        sorted_src[beg + pos] = (int)(p & 0x1FFFF);
    }
}

// ---- fp32 -> fp16 cast (row-major) ----
__global__ void cast_f2h(const float* __restrict__ in, half_t* __restrict__ out, int n4) {
    int t = blockIdx.x * blockDim.x + threadIdx.x;
    if (t < n4) {
        float4 v = *(const float4*)(in + (size_t)t * 4);
        half4v r = {(half_t)v.x, (half_t)v.y, (half_t)v.z, (half_t)v.w};
        *(half4v*)(out + (size_t)t * 4) = r;
    }
}

// ---- weight prep: fragment-contiguous fp16; all 6 weights in one launch ----
template <int C_IN, int C_OUT>
__device__ inline void prep_one(const float* __restrict__ W, half_t* __restrict__ B, int t) {
    constexpr int NCT = C_OUT / 16;
    if (t >= C_IN * C_OUT) return;
    int jj = t & 7;
    int kq = (t >> 3) & 3;
    int c = (t >> 5) & 15;
    int ct = (t >> 9) % NCT;
    int chunk = t / (512 * NCT);
    int k = chunk * 32 + kq * 8 + jj;
    int j = ct * 16 + c;
    B[t] = (half_t)W[(size_t)j * C_IN + k];
}

__global__ __launch_bounds__(256) void prep_all(
    const float* __restrict__ Wl1, const float* __restrict__ Wr1,
    const float* __restrict__ Wl2, const float* __restrict__ Wr2,
    const float* __restrict__ Wl3, const float* __restrict__ Wr3,
    half_t* Bl1, half_t* Br1, half_t* Bl2, half_t* Br2, half_t* Bl3, half_t* Br3) {
    int b = blockIdx.x;
    int tid = threadIdx.x;
    if (b < 256) {  // 4x 128x128 weights, 64 blocks each
        int sel = b >> 6;
        int t = (b & 63) * 256 + tid;
        const float* W = sel == 0 ? Wl1 : sel == 1 ? Wr1 : sel == 2 ? Wl2 : Wr2;
        half_t* B = sel == 0 ? Bl1 : sel == 1 ? Br1 : sel == 2 ? Bl2 : Br2;
        prep_one<128, 128>(W, B, t);
    } else {  // 2x 64x128 weights, 32 blocks each
        int idx = b - 256;
        int sel = idx >> 5;
        int t = (idx & 31) * 256 + tid;
        prep_one<128, 64>(sel == 0 ? Wl3 : Wr3, sel == 0 ? Bl3 : Br3, t);
    }
}

// ---- gather mean, C=128 rows (256B): 32-lane group/node, 16 lanes x 16B/edge,
//      2 edge-subgroups, unroll x4 -> 8 edges (64B/lane) in flight ----
__global__ __launch_bounds__(256) void gather_mean(
    const half_t* __restrict__ h, const int* __restrict__ row_ptr,
    const int* __restrict__ sorted_src, half_t* __restrict__ mean, int n) {
    int node = blockIdx.x * 8 + (threadIdx.x >> 5);
    if (node >= n) return;
    int lane = threadIdx.x & 31;
    int sub = lane >> 4;   // edge subgroup 0..1
    int col = lane & 15;   // 16B column slice
    int beg = row_ptr[node], end = row_ptr[node + 1];
    const half_t* base = h + col * 8;
    float a0 = 0.f, a1 = 0.f, a2 = 0.f, a3 = 0.f, a4 = 0.f, a5 = 0.f, a6 = 0.f, a7 = 0.f;
    int j = beg + sub;
    for (; j + 6 < end; j += 8) {
        int s0 = sorted_src[j];
        int s1 = sorted_src[j + 2];
        int s2 = sorted_src[j + 4];
        int s3 = sorted_src[j + 6];
        half8v v0 = *(const half8v*)(base + (size_t)s0 * 128);
        half8v v1 = *(const half8v*)(base + (size_t)s1 * 128);
        half8v v2 = *(const half8v*)(base + (size_t)s2 * 128);
        half8v v3 = *(const half8v*)(base + (size_t)s3 * 128);
        a0 += ((float)v0[0] + (float)v1[0]) + ((float)v2[0] + (float)v3[0]);
        a1 += ((float)v0[1] + (float)v1[1]) + ((float)v2[1] + (float)v3[1]);
        a2 += ((float)v0[2] + (float)v1[2]) + ((float)v2[2] + (float)v3[2]);
        a3 += ((float)v0[3] + (float)v1[3]) + ((float)v2[3] + (float)v3[3]);
        a4 += ((float)v0[4] + (float)v1[4]) + ((float)v2[4] + (float)v3[4]);
        a5 += ((float)v0[5] + (float)v1[5]) + ((float)v2[5] + (float)v3[5]);
        a6 += ((float)v0[6] + (float)v1[6]) + ((float)v2[6] + (float)v3[6]);
        a7 += ((float)v0[7] + (float)v1[7]) + ((float)v2[7] + (float)v3[7]);
    }
    for (; j < end; j += 2) {
        int s0 = sorted_src[j];
        half8v v0 = *(const half8v*)(base + (size_t)s0 * 128);
        a0 += (float)v0[0]; a1 += (float)v0[1]; a2 += (float)v0[2]; a3 += (float)v0[3];
        a4 += (float)v0[4]; a5 += (float)v0[5]; a6 += (float)v0[6]; a7 += (float)v0[7];
    }
    a0 += __shfl_xor(a0, 16); a1 += __shfl_xor(a1, 16);
    a2 += __shfl_xor(a2, 16); a3 += __shfl_xor(a3, 16);
    a4 += __shfl_xor(a4, 16); a5 += __shfl_xor(a5, 16);
    a6 += __shfl_xor(a6, 16); a7 += __shfl_xor(a7, 16);
    if (sub == 0) {
        float inv = (end > beg) ? 1.0f / (float)(end - beg) : 0.0f;
        half8v r = {(half_t)(a0 * inv), (half_t)(a1 * inv), (half_t)(a2 * inv), (half_t)(a3 * inv),
                    (half_t)(a4 * inv), (half_t)(a5 * inv), (half_t)(a6 * inv), (half_t)(a7 * inv)};
        *(half8v*)(mean + (size_t)node * 128 + col * 8) = r;
    }
}

// ---- gather mean, C=64 rows (128B): 8 lanes x 16B/edge, 4 subgroups, unroll x2 ----
__global__ __launch_bounds__(256) void gather_mean64(
    const half_t* __restrict__ z, const int* __restrict__ row_ptr,
    const int* __restrict__ sorted_src, half_t* __restrict__ mean, int n) {
    int node = blockIdx.x * 8 + (threadIdx.x >> 5);
    if (node >= n) return;
    int lane = threadIdx.x & 31;
    int sub = lane >> 3;   // edge subgroup 0..3
    int col = lane & 7;    // 16B column slice
    int beg = row_ptr[node], end = row_ptr[node + 1];
    const half_t* base = z + col * 8;
    float a0 = 0.f, a1 = 0.f, a2 = 0.f, a3 = 0.f, a4 = 0.f, a5 = 0.f, a6 = 0.f, a7 = 0.f;
    int j = beg + sub;
    for (; j + 4 < end; j += 8) {
        int s0 = sorted_src[j];
        int s1 = sorted_src[j + 4];
        half8v v0 = *(const half8v*)(base + (size_t)s0 * 64);
        half8v v1 = *(const half8v*)(base + (size_t)s1 * 64);
        a0 += (float)v0[0] + (float)v1[0];
        a1 += (float)v0[1] + (float)v1[1];
        a2 += (float)v0[2] + (float)v1[2];
        a3 += (float)v0[3] + (float)v1[3];
        a4 += (float)v0[4] + (float)v1[4];
        a5 += (float)v0[5] + (float)v1[5];
        a6 += (float)v0[6] + (float)v1[6];
        a7 += (float)v0[7] + (float)v1[7];
    }
    for (; j < end; j += 4) {
        int s0 = sorted_src[j];
        half8v v0 = *(const half8v*)(base + (size_t)s0 * 64);
        a0 += (float)v0[0]; a1 += (float)v0[1]; a2 += (float)v0[2]; a3 += (float)v0[3];
        a4 += (float)v0[4]; a5 += (float)v0[5]; a6 += (float)v0[6]; a7 += (float)v0[7];
    }
#pragma unroll
    for (int m = 8; m <= 16; m <<= 1) {
        a0 += __shfl_xor(a0, m); a1 += __shfl_xor(a1, m);
        a2 += __shfl_xor(a2, m); a3 += __shfl_xor(a3, m);
        a4 += __shfl_xor(a4, m); a5 += __shfl_xor(a5, m);
        a6 += __shfl_xor(a6, m); a7 += __shfl_xor(a7, m);
    }
    if (sub == 0) {
        float inv = (end > beg) ? 1.0f / (float)(end - beg) : 0.0f;
        half8v r = {(half_t)(a0 * inv), (half_t)(a1 * inv), (half_t)(a2 * inv), (half_t)(a3 * inv),
                    (half_t)(a4 * inv), (half_t)(a5 * inv), (half_t)(a6 * inv), (half_t)(a7 * inv)};
        *(half8v*)(mean + (size_t)node * 64 + col * 8) = r;
    }
}

// ---- MFMA two-stage layer (layers 1,2): out16 = relu( mean@Wl^T + bias + root@Wr^T ) ----
template <int C_OUT>
__global__ __launch_bounds__(256) void mfma_layer(
    const half_t* __restrict__ rootA, const half_t* __restrict__ meanA,
    const half_t* __restrict__ Bl, const half_t* __restrict__ Br,
    const float* __restrict__ bias, half_t* __restrict__ out16, int n) {
    constexpr int NCT = C_OUT / 16;
    int tid = threadIdx.x;
    int w = tid >> 6;
    int l = tid & 63;
    int c = l & 15;
    int q = l >> 4;
    int row = blockIdx.x * 64 + w * 16 + c;
    int rowc = min(row, n - 1);

    float4v acc[NCT];
#pragma unroll
    for (int i = 0; i < NCT; i++) acc[i] = (float4v){0.f, 0.f, 0.f, 0.f};

#pragma unroll
    for (int s = 0; s < 2; s++) {
        const half_t* A = (s == 0 ? meanA : rootA) + (size_t)rowc * 128 + q * 8;
        const half_t* B = (s == 0 ? Bl : Br) + (size_t)(c * 4 + q) * 8;
#pragma unroll
        for (int ch = 0; ch < 4; ch++) {
            half8v a = *(const half8v*)(A + ch * 32);
            half8v b[NCT];
#pragma unroll
            for (int t2 = 0; t2 < NCT; t2++)
                b[t2] = *(const half8v*)(B + (size_t)ch * (NCT * 512) + t2 * 512);
#pragma unroll
            for (int t2 = 0; t2 < NCT; t2++)
                acc[t2] = __builtin_amdgcn_mfma_f32_16x16x32_f16(a, b[t2], acc[t2], 0, 0, 0);
        }
    }

    int orow0 = blockIdx.x * 64 + w * 16 + q * 4;
#pragma unroll
    for (int t2 = 0; t2 < NCT; t2++) {
        int col = t2 * 16 + c;
        float bv = bias[col];
#pragma unroll
        for (int r = 0; r < 4; r++) {
            int nrow = orow0 + r;
            if (nrow < n)
                out16[(size_t)nrow * C_OUT + col] = (half_t)fmaxf(acc[t2][r] + bv, 0.f);
        }
    }
}

// ---- MFMA single-stage (layer 3 pre/root): K=128, A row-major ----
template <int C_OUT, bool HAS_ADD, bool OUT32>
__global__ __launch_bounds__(256) void mfma_single(
    const half_t* __restrict__ A_, const half_t* __restrict__ Bp,
    const half_t* __restrict__ addv, const float* __restrict__ bias,
    float* __restrict__ out32, half_t* __restrict__ out16, int n) {
    constexpr int NCT = C_OUT / 16;
    int tid = threadIdx.x;
    int w = tid >> 6;
    int l = tid & 63;
    int c = l & 15;
    int q = l >> 4;
    int row = blockIdx.x * 64 + w * 16 + c;
    int rowc = min(row, n - 1);

    float4v acc[NCT];
#pragma unroll
    for (int i = 0; i < NCT; i++) acc[i] = (float4v){0.f, 0.f, 0.f, 0.f};

    const half_t* A = A_ + (size_t)rowc * 128 + q * 8;
    const half_t* B = Bp + (size_t)(c * 4 + q) * 8;
#pragma unroll
    for (int ch = 0; ch < 4; ch++) {
        half8v a = *(const half8v*)(A + ch * 32);
        half8v b[NCT];
#pragma unroll
        for (int t2 = 0; t2 < NCT; t2++)
            b[t2] = *(const half8v*)(B + (size_t)ch * (NCT * 512) + t2 * 512);
#pragma unroll
        for (int t2 = 0; t2 < NCT; t2++)
            acc[t2] = __builtin_amdgcn_mfma_f32_16x16x32_f16(a, b[t2], acc[t2], 0, 0, 0);
    }

    int orow0 = blockIdx.x * 64 + w * 16 + q * 4;
#pragma unroll
    for (int t2 = 0; t2 < NCT; t2++) {
        int col = t2 * 16 + c;
        float bv = bias ? bias[col] : 0.f;
#pragma unroll
        for (int r = 0; r < 4; r++) {
            int nrow = orow0 + r;
            if (nrow < n) {
                float v = acc[t2][r] + bv;
                if (HAS_ADD) v += (float)addv[(size_t)nrow * C_OUT + col];
                if (OUT32) out32[(size_t)nrow * C_OUT + col] = v;
                else       out16[(size_t)nrow * C_OUT + col] = (half_t)v;
            }
        }
    }
}

extern "C" void kernel_launch(void* const* d_in, const int* in_sizes, int n_in,
                              void* d_out, int out_size, void* d_ws, size_t ws_size,
                              hipStream_t stream) {
    const float* x   = (const float*)d_in[0];
    const int*   ei  = (const int*)d_in[1];
    const float* Wl1 = (const float*)d_in[2];
    const float* bl1 = (const float*)d_in[3];
    const float* Wr1 = (const float*)d_in[4];
    const float* Wl2 = (const float*)d_in[5];
    const float* bl2 = (const float*)d_in[6];
    const float* Wr2 = (const float*)d_in[7];
    const float* Wl3 = (const float*)d_in[8];
    const float* bl3 = (const float*)d_in[9];
    const float* Wr3 = (const float*)d_in[10];

    const int N = NN;
    const int E = in_sizes[1] / 2;
    const int* src = ei;
    const int* dst = ei + E;

    char* ws = (char*)d_ws;
    half_t* xh    = (half_t*)ws;                      // N*128
    half_t* hh    = xh + (size_t)N * 128;             // N*128
    half_t* meanh = hh + (size_t)N * 128;             // N*128 (aliased: z | meanz in layer 3)
    half_t* z     = meanh;                            // N*64
    half_t* meanz = meanh + (size_t)N * 64;           // N*64
    int* ghist    = (int*)(meanh + (size_t)N * 128);  // 1024
    int* cptr     = ghist + 1024;                     // 1025 (pad 1028)
    int* cfill    = cptr + 1028;                      // 1024
    int* row_ptr  = cfill + 1024;                     // N+1 (pad N+4)
    unsigned int* coarse = (unsigned int*)(row_ptr + N + 4);  // E
    int* sorted_src = (int*)(coarse + E);             // E
    half_t* Bl1 = (half_t*)(sorted_src + E);
    half_t* Br1 = Bl1 + 128 * 128;
    half_t* Bl2 = Br1 + 128 * 128;
    half_t* Br2 = Bl2 + 128 * 128;
    half_t* Bl3 = Br2 + 128 * 128;                    // 64*128
    half_t* Br3 = Bl3 + 64 * 128;

    // casts + weight prep
    cast_f2h<<<(N * 128 / 4 + 255) / 256, 256, 0, stream>>>(x, xh, N * 128 / 4);
    prep_all<<<320, 256, 0, stream>>>(Wl1, Wr1, Wl2, Wr2, Wl3, Wr3,
                                      Bl1, Br1, Bl2, Br2, Bl3, Br3);

    // CSR build: two-level counting sort
    const int sort_blocks = (E + CHUNK - 1) / CHUNK;
    hipMemsetAsync(ghist, 0, 1024 * 4, stream);
    coarse_hist_kernel<<<sort_blocks, 256, 0, stream>>>(dst, ghist, E);
    coarse_scan_kernel<<<1, 1024, 0, stream>>>(ghist, cptr, cfill, row_ptr, N, E);
    partition_kernel<<<sort_blocks, 256, 0, stream>>>(src, dst, cfill, coarse, E);
    fine_sort_kernel<<<(N + 127) / 128, 256, 0, stream>>>(coarse, cptr, row_ptr, sorted_src, N);

    const int agg_blocks = (N + 7) / 8;
    const int gemm_blocks = (N + 63) / 64;

    // Layer 1: xh -> hh (relu)
    gather_mean<<<agg_blocks, 256, 0, stream>>>(xh, row_ptr, sorted_src, meanh, N);
    mfma_layer<128><<<gemm_blocks, 256, 0, stream>>>(xh, meanh, Bl1, Br1, bl1, hh, N);

    // Layer 2: hh -> hh (relu)
    gather_mean<<<agg_blocks, 256, 0, stream>>>(hh, row_ptr, sorted_src, meanh, N);
    mfma_layer<128><<<gemm_blocks, 256, 0, stream>>>(hh, meanh, Bl2, Br2, bl2, hh, N);

    // Layer 3 (transform-before-aggregate):
    //   z = hh@Wl3^T ; meanz = gather-mean(z) ; out = meanz + bl3 + hh@Wr3^T
    mfma_single<64, false, false><<<gemm_blocks, 256, 0, stream>>>(
        hh, Bl3, nullptr, nullptr, nullptr, z, N);
    gather_mean64<<<agg_blocks, 256, 0, stream>>>(z, row_ptr, sorted_src, meanz, N);
    mfma_single<64, true, true><<<gemm_blocks, 256, 0, stream>>>(
        hh, Br3, meanz, bl3, (float*)d_out, nullptr, N);
}